// Round 1
// baseline (791.560 us; speedup 1.0000x reference)
//
#include <hip/hip_runtime.h>
#include <math.h>

#define D 32
#define SLOPE 0.2f
#define GAT_EPS 1e-16f

__device__ __forceinline__ void atomicMaxFloat(float* addr, float val) {
    // Works for mixed-sign floats when addr initialized to -inf:
    // non-negative floats keep their order as ints (atomicMax int),
    // negative floats reverse order as unsigned (atomicMin uint).
    if (val >= 0.0f) {
        atomicMax((int*)addr, __float_as_int(val));
    } else {
        atomicMin((unsigned int*)addr, (unsigned int)__float_as_int(val));
    }
}

// h = x @ W ; s_src[n] = h[n]·a_src ; s_dst[n] = h[n]·a_dst
__global__ void k_linear(const float* __restrict__ x, const float* __restrict__ W,
                         const float* __restrict__ a_src, const float* __restrict__ a_dst,
                         float* __restrict__ h, float* __restrict__ ssrc,
                         float* __restrict__ sdst, int N) {
    __shared__ float Ws[D * D];
    __shared__ float xs[8 * D];
    int tid = threadIdx.x;
    for (int i = tid; i < D * D; i += 256) Ws[i] = W[i];
    int base = blockIdx.x * 8;
    int gidx = base * D + tid;
    xs[tid] = (gidx < N * D) ? x[gidx] : 0.0f;
    __syncthreads();
    int r = tid >> 5, d = tid & 31;
    int n = base + r;
    if (n >= N) return;
    float acc = 0.0f;
#pragma unroll
    for (int k = 0; k < D; ++k) acc += xs[r * D + k] * Ws[k * D + d];
    h[n * D + d] = acc;
    float vs = acc * a_src[d];
    float vd = acc * a_dst[d];
#pragma unroll
    for (int off = 16; off > 0; off >>= 1) {
        vs += __shfl_xor(vs, off, 32);
        vd += __shfl_xor(vd, off, 32);
    }
    if (d == 0) { ssrc[n] = vs; sdst[n] = vd; }
}

__global__ void k_init(float* __restrict__ m, float* __restrict__ denom,
                       float* __restrict__ acc, int N) {
    int i = blockIdx.x * blockDim.x + threadIdx.x;
    if (i < N) { m[i] = -INFINITY; denom[i] = 0.0f; }
    if (i < N * D) acc[i] = 0.0f;
}

__global__ void k_logit_max(const int* __restrict__ src, const int* __restrict__ dst,
                            const float* __restrict__ ssrc, const float* __restrict__ sdst,
                            float* __restrict__ m, int E, int Etot) {
    int e = blockIdx.x * blockDim.x + threadIdx.x;
    if (e >= Etot) return;
    int s, t;
    if (e < E) { s = src[e]; t = dst[e]; } else { s = t = e - E; }
    float l = ssrc[s] + sdst[t];
    l = (l >= 0.0f) ? l : SLOPE * l;
    atomicMaxFloat(&m[t], l);
}

__global__ void k_exp_denom(const int* __restrict__ src, const int* __restrict__ dst,
                            const float* __restrict__ ssrc, const float* __restrict__ sdst,
                            const float* __restrict__ m, float* __restrict__ eedge,
                            float* __restrict__ denom, int E, int Etot) {
    int e = blockIdx.x * blockDim.x + threadIdx.x;
    if (e >= Etot) return;
    int s, t;
    if (e < E) { s = src[e]; t = dst[e]; } else { s = t = e - E; }
    float l = ssrc[s] + sdst[t];
    l = (l >= 0.0f) ? l : SLOPE * l;
    float ev = expf(l - m[t]);
    eedge[e] = ev;
    atomicAdd(&denom[t], ev);
}

// one thread per (edge, d): 32 coalesced lanes gather h[src] row, scatter-add acc[dst] row
__global__ void k_aggregate(const int* __restrict__ src, const int* __restrict__ dst,
                            const float* __restrict__ eedge, const float* __restrict__ denom,
                            const float* __restrict__ h, float* __restrict__ acc,
                            int E, int Etot) {
    int idx = blockIdx.x * blockDim.x + threadIdx.x;
    int e = idx >> 5;
    if (e >= Etot) return;
    int d = idx & 31;
    int s, t;
    if (e < E) { s = src[e]; t = dst[e]; } else { s = t = e - E; }
    float alpha = eedge[e] / (denom[t] + GAT_EPS);
    atomicAdd(&acc[t * D + d], alpha * h[s * D + d]);
}

__global__ void k_bias_elu(const float* __restrict__ acc, const float* __restrict__ b,
                           float* __restrict__ out, int ND) {
    int i = blockIdx.x * blockDim.x + threadIdx.x;
    if (i >= ND) return;
    float v = acc[i] + b[i & (D - 1)];
    out[i] = (v > 0.0f) ? v : expm1f(v);
}

extern "C" void kernel_launch(void* const* d_in, const int* in_sizes, int n_in,
                              void* d_out, int out_size, void* d_ws, size_t ws_size,
                              hipStream_t stream) {
    const float* x   = (const float*)d_in[0];
    const int*   ei  = (const int*)d_in[1];
    const float* W1  = (const float*)d_in[2];
    const float* as1 = (const float*)d_in[3];
    const float* ad1 = (const float*)d_in[4];
    const float* b1  = (const float*)d_in[5];
    const float* W2  = (const float*)d_in[6];
    const float* as2 = (const float*)d_in[7];
    const float* ad2 = (const float*)d_in[8];
    const float* b2  = (const float*)d_in[9];

    const int N = in_sizes[0] / D;
    const int E = in_sizes[1] / 2;
    const int Etot = E + N;

    float* out  = (float*)d_out;
    float* xbar = out;                    // first output chunk
    float* z    = out + (size_t)N * D;    // second output chunk (also layer-2 input)

    float* ws    = (float*)d_ws;
    float* h     = ws;                 // N*D
    float* ssrc  = h + (size_t)N * D;  // N
    float* sdst  = ssrc + N;           // N
    float* m     = sdst + N;           // N
    float* denom = m + N;              // N
    float* eedge = denom + N;          // Etot
    float* accb  = eedge + Etot;       // N*D

    const int* srcA = ei;
    const int* dstA = ei + E;

    const int ND = N * D;
    const int gLin  = (N + 7) / 8;
    const int gInit = (ND + 255) / 256;
    const int gEdge = (Etot + 255) / 256;
    const int gAgg  = (int)(((long long)Etot * 32 + 255) / 256);

    // ---- layer 1: x -> z ----
    k_linear<<<gLin, 256, 0, stream>>>(x, W1, as1, ad1, h, ssrc, sdst, N);
    k_init<<<gInit, 256, 0, stream>>>(m, denom, accb, N);
    k_logit_max<<<gEdge, 256, 0, stream>>>(srcA, dstA, ssrc, sdst, m, E, Etot);
    k_exp_denom<<<gEdge, 256, 0, stream>>>(srcA, dstA, ssrc, sdst, m, eedge, denom, E, Etot);
    k_aggregate<<<gAgg, 256, 0, stream>>>(srcA, dstA, eedge, denom, h, accb, E, Etot);
    k_bias_elu<<<gInit, 256, 0, stream>>>(accb, b1, z, ND);

    // ---- layer 2: z -> xbar ----
    k_linear<<<gLin, 256, 0, stream>>>(z, W2, as2, ad2, h, ssrc, sdst, N);
    k_init<<<gInit, 256, 0, stream>>>(m, denom, accb, N);
    k_logit_max<<<gEdge, 256, 0, stream>>>(srcA, dstA, ssrc, sdst, m, E, Etot);
    k_exp_denom<<<gEdge, 256, 0, stream>>>(srcA, dstA, ssrc, sdst, m, eedge, denom, E, Etot);
    k_aggregate<<<gAgg, 256, 0, stream>>>(srcA, dstA, eedge, denom, h, accb, E, Etot);
    k_bias_elu<<<gInit, 256, 0, stream>>>(accb, b2, xbar, ND);
}

// Round 2
// 619.901 us; speedup vs baseline: 1.2769x; 1.2769x over previous
//
#include <hip/hip_runtime.h>
#include <math.h>

#define D 32
#define SLOPE 0.2f
#define GAT_EPS 1e-16f

// ---------------- binning: build dst-sorted CSR (shared by both layers) ----------------

__global__ void k_zero(int* __restrict__ cnt, int N) {
    int i = blockIdx.x * blockDim.x + threadIdx.x;
    if (i < N) cnt[i] = 0;
}

__global__ void k_hist(const int* __restrict__ dst, int* __restrict__ cnt, int E, int Etot) {
    int e = blockIdx.x * blockDim.x + threadIdx.x;
    if (e >= Etot) return;
    int t = (e < E) ? dst[e] : e - E;
    atomicAdd(&cnt[t], 1);
}

// single block of 256: exclusive scan of cnt -> start; cnt becomes the scatter cursor
__global__ void k_scan(int* __restrict__ cnt, int* __restrict__ start, int N, int Etot) {
    __shared__ int sums[256];
    int t = threadIdx.x;
    int chunk = (N + 255) / 256;
    int lo = t * chunk, hi = min(N, lo + chunk);
    int s = 0;
    for (int i = lo; i < hi; ++i) s += cnt[i];
    sums[t] = s;
    __syncthreads();
    for (int off = 1; off < 256; off <<= 1) {
        int v = 0;
        if (t >= off) v = sums[t - off];
        __syncthreads();
        if (t >= off) sums[t] += v;
        __syncthreads();
    }
    int run = (t == 0) ? 0 : sums[t - 1];
    for (int i = lo; i < hi; ++i) {
        int c = cnt[i];
        start[i] = run;
        cnt[i] = run;   // cursor for k_scatter
        run += c;
    }
    if (t == 255) start[N] = Etot;
}

__global__ void k_scatter(const int* __restrict__ src, const int* __restrict__ dst,
                          int* __restrict__ cursor, int* __restrict__ ssorted,
                          int E, int Etot) {
    int e = blockIdx.x * blockDim.x + threadIdx.x;
    if (e >= Etot) return;
    int s, t;
    if (e < E) { s = src[e]; t = dst[e]; } else { s = t = e - E; }
    int p = atomicAdd(&cursor[t], 1);
    ssorted[p] = s;
}

// ---------------- per-layer ----------------

// h = x @ W ; ssrc[n] = h[n]·a_src ; sdst[n] = h[n]·a_dst
__global__ void k_linear(const float* __restrict__ x, const float* __restrict__ W,
                         const float* __restrict__ a_src, const float* __restrict__ a_dst,
                         float* __restrict__ h, float* __restrict__ ssrc,
                         float* __restrict__ sdst, int N) {
    __shared__ float Ws[D * D];
    __shared__ float xs[8 * D];
    int tid = threadIdx.x;
    for (int i = tid; i < D * D; i += 256) Ws[i] = W[i];
    int base = blockIdx.x * 8;
    int gidx = base * D + tid;
    xs[tid] = (gidx < N * D) ? x[gidx] : 0.0f;
    __syncthreads();
    int r = tid >> 5, d = tid & 31;
    int n = base + r;
    if (n >= N) return;
    float acc = 0.0f;
#pragma unroll
    for (int k = 0; k < D; ++k) acc += xs[r * D + k] * Ws[k * D + d];
    h[n * D + d] = acc;
    float vs = acc * a_src[d];
    float vd = acc * a_dst[d];
#pragma unroll
    for (int off = 16; off > 0; off >>= 1) {
        vs += __shfl_xor(vs, off, 32);
        vd += __shfl_xor(vd, off, 32);
    }
    if (d == 0) { ssrc[n] = vs; sdst[n] = vd; }
}

// one wave (64 lanes) per node: max + sum(exp) over its dst-sorted edge list. No atomics.
__global__ void k_node_softmax(const int* __restrict__ ssorted, const int* __restrict__ start,
                               const float* __restrict__ ssrc, const float* __restrict__ sdst,
                               float* __restrict__ m, float* __restrict__ denom, int N) {
    int wid = (int)((blockIdx.x * blockDim.x + threadIdx.x) >> 6);
    int lane = threadIdx.x & 63;
    if (wid >= N) return;
    int st = start[wid], en = start[wid + 1];
    float sd = sdst[wid];
    float lmax = -INFINITY;
    for (int i = st + lane; i < en; i += 64) {
        float l = ssrc[ssorted[i]] + sd;
        l = (l >= 0.0f) ? l : SLOPE * l;
        lmax = fmaxf(lmax, l);
    }
#pragma unroll
    for (int off = 32; off > 0; off >>= 1) lmax = fmaxf(lmax, __shfl_xor(lmax, off, 64));
    float sum = 0.0f;
    for (int i = st + lane; i < en; i += 64) {
        float l = ssrc[ssorted[i]] + sd;
        l = (l >= 0.0f) ? l : SLOPE * l;
        sum += __expf(l - lmax);
    }
#pragma unroll
    for (int off = 32; off > 0; off >>= 1) sum += __shfl_xor(sum, off, 64);
    if (lane == 0) { m[wid] = lmax; denom[wid] = sum; }
}

// one wave per node: lanes = (edge-slot 0/1) x (dim 0..31); gather h[src] rows,
// accumulate in registers, single write per output element. Bias+ELU fused.
__global__ void k_node_agg(const int* __restrict__ ssorted, const int* __restrict__ start,
                           const float* __restrict__ ssrc, const float* __restrict__ sdst,
                           const float* __restrict__ m, const float* __restrict__ denom,
                           const float* __restrict__ h, const float* __restrict__ b,
                           float* __restrict__ out, int N) {
    int wid = (int)((blockIdx.x * blockDim.x + threadIdx.x) >> 6);
    int lane = threadIdx.x & 63;
    if (wid >= N) return;
    int el = lane >> 5, d = lane & 31;
    int st = start[wid], en = start[wid + 1];
    float sd = sdst[wid], mn = m[wid], den = denom[wid];
    float acc = 0.0f;
    for (int i = st + el; i < en; i += 2) {
        int s = ssorted[i];
        float l = ssrc[s] + sd;
        l = (l >= 0.0f) ? l : SLOPE * l;
        float a = __expf(l - mn);
        acc += a * h[s * D + d];
    }
    acc += __shfl_xor(acc, 32, 64);
    if (el == 0) {
        float v = acc / (den + GAT_EPS) + b[d];
        out[wid * D + d] = (v > 0.0f) ? v : expm1f(v);
    }
}

extern "C" void kernel_launch(void* const* d_in, const int* in_sizes, int n_in,
                              void* d_out, int out_size, void* d_ws, size_t ws_size,
                              hipStream_t stream) {
    const float* x   = (const float*)d_in[0];
    const int*   ei  = (const int*)d_in[1];
    const float* W1  = (const float*)d_in[2];
    const float* as1 = (const float*)d_in[3];
    const float* ad1 = (const float*)d_in[4];
    const float* b1  = (const float*)d_in[5];
    const float* W2  = (const float*)d_in[6];
    const float* as2 = (const float*)d_in[7];
    const float* ad2 = (const float*)d_in[8];
    const float* b2  = (const float*)d_in[9];

    const int N = in_sizes[0] / D;
    const int E = in_sizes[1] / 2;
    const int Etot = E + N;

    float* out  = (float*)d_out;
    float* xbar = out;                    // first output chunk
    float* z    = out + (size_t)N * D;    // second output chunk (layer-2 input)

    float* ws      = (float*)d_ws;
    float* h       = ws;                   // N*D
    float* ssrc    = h + (size_t)N * D;    // N
    float* sdst    = ssrc + N;             // N
    float* m       = sdst + N;             // N
    float* denom   = m + N;                // N
    int*   cnt     = (int*)(denom + N);    // N (histogram, then scatter cursor)
    int*   startA  = cnt + N;              // N+1
    int*   ssorted = startA + N + 1;       // Etot

    const int* srcA = ei;
    const int* dstA = ei + E;

    const int gN    = (N + 255) / 256;
    const int gEdge = (Etot + 255) / 256;
    const int gLin  = (N + 7) / 8;
    const int gWave = (N + 3) / 4;         // 4 waves (nodes) per 256-thread block

    // ---- build CSR once; reused by both layers ----
    k_zero<<<gN, 256, 0, stream>>>(cnt, N);
    k_hist<<<gEdge, 256, 0, stream>>>(dstA, cnt, E, Etot);
    k_scan<<<1, 256, 0, stream>>>(cnt, startA, N, Etot);
    k_scatter<<<gEdge, 256, 0, stream>>>(srcA, dstA, cnt, ssorted, E, Etot);

    // ---- layer 1: x -> z ----
    k_linear<<<gLin, 256, 0, stream>>>(x, W1, as1, ad1, h, ssrc, sdst, N);
    k_node_softmax<<<gWave, 256, 0, stream>>>(ssorted, startA, ssrc, sdst, m, denom, N);
    k_node_agg<<<gWave, 256, 0, stream>>>(ssorted, startA, ssrc, sdst, m, denom, h, b1, z, N);

    // ---- layer 2: z -> xbar ----
    k_linear<<<gLin, 256, 0, stream>>>(z, W2, as2, ad2, h, ssrc, sdst, N);
    k_node_softmax<<<gWave, 256, 0, stream>>>(ssorted, startA, ssrc, sdst, m, denom, N);
    k_node_agg<<<gWave, 256, 0, stream>>>(ssorted, startA, ssrc, sdst, m, denom, h, b2, xbar, N);
}